// Round 6
// baseline (1260.151 us; speedup 1.0000x reference)
//
#include <hip/hip_runtime.h>

// CapsuleLayer dynamic routing, MI355X (gfx950).
// B=64, I=2048 (input caps), L=16 (in_dim), J=64 (out caps), K=32 (out dim).
// u_hat never materialized. Logits are linear in u_hat (b_r = (sum of prior v).u_hat).
// r=0: s0 pass fuses W fp32->f16 cast (reads W once = HBM floor), uniform c=1/64.
// r=1,2: ONE fused kernel per iteration (one Wh stream instead of two):
//   block = 8 waves owns ALL 64 j for an 8-i chunk (grid 256 = 1 block/CU);
//   phase1: e[j][i][b] = exp(wv.u_hat) via MFMA -> 64 KB LDS (z-contraction
//           split into 4 independent FMA chains; no max-subtraction: |z| <~ 6)
//   phase2: rD[i][b] = 1/sum_j e, entirely in LDS (2-way banks = free)
//   phase3: s partials += (e*rD) * u_hat (af re-read = L2/L3 hit), flush per j.
// reduce: sum chunk partials, squash, maintain wv fragments (f16, MFMA D-layout).
// MFMA 32x32x16 f16: D rows k = (r&3)+8*(r>>2)+4*(lane>>5), cols b = lane&31.

#define B_ 64
#define I_ 2048
#define L_ 16
#define J_ 64
#define K_ 32
#define N_ 2048   // J_*K_
#define SCHF 256  // fused pass chunk count (= grid, 8 i per block)
#define SCH0 64   // r0 pass chunk count (grid SCH0*8, 32 i per wave)

typedef _Float16 half8_t __attribute__((ext_vector_type(8)));
typedef float f32x16 __attribute__((ext_vector_type(16)));
typedef float float4_t __attribute__((ext_vector_type(4)));

__device__ __forceinline__ f32x16 fzero16() {
    f32x16 z;
#pragma unroll
    for (int r = 0; r < 16; ++r) z[r] = 0.f;
    return z;
}

// ---- cast x: [b][i][l] fp32 -> Xh[i][b][l] f16
__global__ __launch_bounds__(256) void cast_x_kernel(const float* __restrict__ X,
                                                     _Float16* __restrict__ Xh) {
    unsigned tid = blockIdx.x * 256u + threadIdx.x;  // (i,b), b fastest
    unsigned b = tid & 63u;
    unsigned i = tid >> 6;
    const float4_t* src = (const float4_t*)(X + (size_t)(b * I_ + i) * L_);
    float4_t f0 = src[0], f1 = src[1], f2 = src[2], f3 = src[3];
    half8_t h0, h1;
#pragma unroll
    for (int e = 0; e < 4; ++e) {
        h0[e] = (_Float16)f0[e];
        h0[4 + e] = (_Float16)f1[e];
        h1[e] = (_Float16)f2[e];
        h1[4 + e] = (_Float16)f3[e];
    }
    _Float16* dst = Xh + (size_t)(i * B_ + b) * L_;
    *(half8_t*)dst = h0;
    *(half8_t*)(dst + 8) = h1;
}

// ---- r0 pass: uniform c; fused W fp32 read + f16 cast (writes Wh) + s0 partials.
// Grid: SCH0*8 blocks x 512 threads; wave owns j = (blk&7)*8 + w, streams 32 i.
__global__ __launch_bounds__(512) void s0_cast_kernel(const float* __restrict__ Wf,
                                                      _Float16* __restrict__ Wh_out,
                                                      const _Float16* __restrict__ Xh,
                                                      _Float16* __restrict__ parts) {
    const int tid = threadIdx.x;
    const int w = tid >> 6;
    const int l = tid & 63;
    const int h2 = l >> 5;
    const int kb = l & 31;
    const int chunk = blockIdx.x >> 3;
    const int jq = blockIdx.x & 7;
    const int j = jq * 8 + w;
    const int ICH = I_ / SCH0;

    float s0[16], s1[16];
#pragma unroll
    for (int r = 0; r < 16; ++r) { s0[r] = 0.f; s1[r] = 0.f; }

    const int i0 = chunk * ICH;
    for (int ii = 0; ii < ICH; ++ii) {
        const int i = i0 + ii;
        const _Float16* xb = Xh + (size_t)i * (B_ * L_);
        half8_t xf0 = *(const half8_t*)(xb + kb * L_ + 8 * h2);
        half8_t xf1 = *(const half8_t*)(xb + (32 + kb) * L_ + 8 * h2);
        const float4_t* wsrc =
            (const float4_t*)(Wf + ((size_t)(j * I_ + i) * K_ + kb) * L_ + 8 * h2);
        float4_t a0 = wsrc[0], a1 = wsrc[1];
        half8_t af;
#pragma unroll
        for (int e = 0; e < 4; ++e) {
            af[e] = (_Float16)a0[e];
            af[4 + e] = (_Float16)a1[e];
        }
        *(half8_t*)(Wh_out + ((size_t)(i * J_ + j) * K_ + kb) * L_ + 8 * h2) = af;
        f32x16 acc0 = __builtin_amdgcn_mfma_f32_32x32x16_f16(af, xf0, fzero16(), 0, 0, 0);
        f32x16 acc1 = __builtin_amdgcn_mfma_f32_32x32x16_f16(af, xf1, fzero16(), 0, 0, 0);
#pragma unroll
        for (int r = 0; r < 16; ++r) {
            s0[r] += acc0[r];
            s1[r] += acc1[r];
        }
    }
#pragma unroll
    for (int r = 0; r < 16; ++r) {
        const int k = (r & 3) + 8 * (r >> 2) + 4 * h2;
        const size_t n = (size_t)j * K_ + k;
        parts[((size_t)kb * SCH0 + chunk) * N_ + n] = (_Float16)s0[r];
        parts[((size_t)(32 + kb) * SCH0 + chunk) * N_ + n] = (_Float16)s1[r];
    }
}

// ---- fused routing pass (r>0): e -> rD -> s partials, one Wh stream.
// Grid: SCHF=256 blocks x 512 threads; block owns all 64 j, i in [8*blk, 8*blk+8).
// wvz layout: [j][h2][b:64][r:16] f16 where k = (r&3) + 8*(r>>2) + 4*h2.
__global__ __launch_bounds__(512) void fused_kernel(const _Float16* __restrict__ Wh,
                                                    const _Float16* __restrict__ Xh,
                                                    const _Float16* __restrict__ wvz,
                                                    _Float16* __restrict__ parts) {
    __shared__ _Float16 elds[J_ * 8 * B_];  // [j][i_local][b] = 64 KB
    __shared__ float rdl[8 * B_];           // [i_local][b]   =  2 KB
    const int tid = threadIdx.x;
    const int w = tid >> 6;
    const int l = tid & 63;
    const int h2 = l >> 5;
    const int kb = l & 31;
    const int chunk = blockIdx.x;
    const int i0 = chunk * 8;

    // x fragments for the 8 local i (live across all phases)
    half8_t xf0[8], xf1[8];
#pragma unroll
    for (int ii = 0; ii < 8; ++ii) {
        const _Float16* xb = Xh + (size_t)(i0 + ii) * (B_ * L_);
        xf0[ii] = *(const half8_t*)(xb + kb * L_ + 8 * h2);
        xf1[ii] = *(const half8_t*)(xb + (32 + kb) * L_ + 8 * h2);
    }

    // ---- phase 1: e[j][i][b] = exp(wv . u_hat); wave w owns j = 8w..8w+7
#pragma unroll
    for (int jj = 0; jj < 8; ++jj) {
        const int j = w * 8 + jj;
        const _Float16* wp = wvz + ((size_t)(j * 2 + h2) * B_ + kb) * 16;
        const half8_t wv00 = *(const half8_t*)wp;         // batch kb,    regs 0-7
        const half8_t wv01 = *(const half8_t*)(wp + 8);   // batch kb,    regs 8-15
        const half8_t wv10 = *(const half8_t*)(wp + 512); // batch kb+32, regs 0-7
        const half8_t wv11 = *(const half8_t*)(wp + 520);
#pragma unroll
        for (int ii = 0; ii < 8; ++ii) {
            half8_t af = *(const half8_t*)(Wh +
                ((size_t)((i0 + ii) * J_ + j) * K_ + kb) * L_ + 8 * h2);
            f32x16 acc0 = __builtin_amdgcn_mfma_f32_32x32x16_f16(af, xf0[ii], fzero16(), 0, 0, 0);
            f32x16 acc1 = __builtin_amdgcn_mfma_f32_32x32x16_f16(af, xf1[ii], fzero16(), 0, 0, 0);
            // 4 independent partial chains per z (dep depth 4, not 16)
            float z0a = 0.f, z0b = 0.f, z0c = 0.f, z0d = 0.f;
            float z1a = 0.f, z1b = 0.f, z1c = 0.f, z1d = 0.f;
#pragma unroll
            for (int r = 0; r < 4; ++r) {
                z0a += acc0[r]      * (float)wv00[r];
                z0b += acc0[r + 4]  * (float)wv00[r + 4];
                z0c += acc0[r + 8]  * (float)wv01[r];
                z0d += acc0[r + 12] * (float)wv01[r + 4];
                z1a += acc1[r]      * (float)wv10[r];
                z1b += acc1[r + 4]  * (float)wv10[r + 4];
                z1c += acc1[r + 8]  * (float)wv11[r];
                z1d += acc1[r + 12] * (float)wv11[r + 4];
            }
            float z0 = (z0a + z0b) + (z0c + z0d);
            float z1 = (z1a + z1b) + (z1c + z1d);
            z0 += __shfl_xor(z0, 32, 64);  // combine disjoint k-halves
            z1 += __shfl_xor(z1, 32, 64);
            // lane l holds full logit of batch l; clamp = NaN insurance
            const float zf = fminf((l < 32) ? z0 : z1, 11.0f);
            elds[((size_t)j * 8 + ii) * B_ + l] = (_Float16)__expf(zf);
        }
    }
    __syncthreads();

    // ---- phase 2: rdl[i][b] = 1/sum_j e ; wave w handles i_local = w, lane = b
    {
        float p0 = 0.f, p1 = 0.f, p2 = 0.f, p3 = 0.f;
#pragma unroll
        for (int jq = 0; jq < 16; ++jq) {
            p0 += (float)elds[((size_t)(jq * 4 + 0) * 8 + w) * B_ + l];
            p1 += (float)elds[((size_t)(jq * 4 + 1) * 8 + w) * B_ + l];
            p2 += (float)elds[((size_t)(jq * 4 + 2) * 8 + w) * B_ + l];
            p3 += (float)elds[((size_t)(jq * 4 + 3) * 8 + w) * B_ + l];
        }
        rdl[w * B_ + l] = 1.0f / ((p0 + p1) + (p2 + p3));
    }
    __syncthreads();

    // ---- phase 3: s partials += (e * rD) * u_hat ; flush per j
#pragma unroll
    for (int jj = 0; jj < 8; ++jj) {
        const int j = w * 8 + jj;
        float s0[16], s1[16];
#pragma unroll
        for (int r = 0; r < 16; ++r) { s0[r] = 0.f; s1[r] = 0.f; }
#pragma unroll
        for (int ii = 0; ii < 8; ++ii) {
            half8_t af = *(const half8_t*)(Wh +
                ((size_t)((i0 + ii) * J_ + j) * K_ + kb) * L_ + 8 * h2);
            f32x16 acc0 = __builtin_amdgcn_mfma_f32_32x32x16_f16(af, xf0[ii], fzero16(), 0, 0, 0);
            f32x16 acc1 = __builtin_amdgcn_mfma_f32_32x32x16_f16(af, xf1[ii], fzero16(), 0, 0, 0);
            const float c0 = (float)elds[((size_t)j * 8 + ii) * B_ + kb] * rdl[ii * B_ + kb];
            const float c1 = (float)elds[((size_t)j * 8 + ii) * B_ + 32 + kb] * rdl[ii * B_ + 32 + kb];
#pragma unroll
            for (int r = 0; r < 16; ++r) {
                s0[r] += c0 * acc0[r];
                s1[r] += c1 * acc1[r];
            }
        }
#pragma unroll
        for (int r = 0; r < 16; ++r) {
            const int k = (r & 3) + 8 * (r >> 2) + 4 * h2;
            const size_t n = (size_t)j * K_ + k;
            parts[((size_t)kb * SCHF + chunk) * N_ + n] = (_Float16)s0[r];
            parts[((size_t)(32 + kb) * SCHF + chunk) * N_ + n] = (_Float16)s1[r];
        }
    }
}

// ---- reduce partials + squash; maintain wv fragments (f16, MFMA D-layout).
// STEP0: s *= 1/64 (uniform softmax), wvz = v. STEP1: wvz += v. STEP2: out = v.
__global__ __launch_bounds__(256) void reduce_kernel(const _Float16* __restrict__ parts,
                                                     _Float16* __restrict__ wvz,
                                                     float* __restrict__ out,
                                                     int SCH, int STEP) {
    const int b = blockIdx.x >> 3;
    const int s = blockIdx.x & 7;
    const int t = threadIdx.x;
    const int n = s * 256 + t;
    const int k = n & 31;
    const int j = n >> 5;
    float acc = 0.f;
    for (int ch = 0; ch < SCH; ++ch) acc += (float)parts[((size_t)b * SCH + ch) * N_ + n];
    if (STEP == 0) acc *= (1.0f / 64.0f);
    // squash over k: 32-lane contiguous groups (k = lane&31)
    float sq = acc * acc;
#pragma unroll
    for (int m = 1; m < 32; m <<= 1) sq += __shfl_xor(sq, m, 64);
    const float scale = sq / (1.0f + sq) / sqrtf(sq + 1e-7f);
    const float v = acc * scale;
    if (STEP == 2) {
        out[(size_t)b * N_ + n] = v;
    } else {
        const int h2 = (k >> 2) & 1;
        const int r = (k & 3) + 4 * (k >> 3);
        const size_t idx = ((size_t)(j * 2 + h2) * B_ + b) * 16 + r;
        const float prev = (STEP == 0) ? 0.f : (float)wvz[idx];
        wvz[idx] = (_Float16)(prev + v);
    }
}

extern "C" void kernel_launch(void* const* d_in, const int* in_sizes, int n_in,
                              void* d_out, int out_size, void* d_ws, size_t ws_size,
                              hipStream_t stream) {
    const float* X = (const float*)d_in[0];  // [64][2048][16]
    const float* W = (const float*)d_in[1];  // [64][2048][32][16]
    float* out = (float*)d_out;              // [64][64][32]
    char* ws = (char*)d_ws;

    const size_t WH_BYTES = (size_t)I_ * J_ * K_ * L_ * 2;   // 134,217,728
    const size_t XH_BYTES = (size_t)I_ * B_ * L_ * 2;        //   4,194,304
    const size_t WVZ_BYTES = (size_t)J_ * 2 * B_ * 16 * 2;   //     262,144
    // parts sized for the larger (fused) layout: B * SCHF * N f16 = 67,108,864
    _Float16* Wh = (_Float16*)ws;
    _Float16* Xh = (_Float16*)(ws + WH_BYTES);
    _Float16* wvz = (_Float16*)(ws + WH_BYTES + XH_BYTES);
    _Float16* parts = (_Float16*)(ws + WH_BYTES + XH_BYTES + WVZ_BYTES);

    cast_x_kernel<<<dim3((B_ * I_) / 256), dim3(256), 0, stream>>>(X, Xh);

    // r = 0: uniform c (1/64 folded into reduce); fused fp32 read + cast + s0
    s0_cast_kernel<<<dim3(SCH0 * 8), dim3(512), 0, stream>>>(W, Wh, Xh, parts);
    reduce_kernel<<<dim3(B_ * 8), dim3(256), 0, stream>>>(parts, wvz, out, SCH0, 0);

    // r = 1: e = exp(v0 . u_hat) -> rD -> s1, one Wh stream
    fused_kernel<<<dim3(SCHF), dim3(512), 0, stream>>>(Wh, Xh, wvz, parts);
    reduce_kernel<<<dim3(B_ * 8), dim3(256), 0, stream>>>(parts, wvz, out, SCHF, 1);

    // r = 2: e = exp((v0+v1) . u_hat) -> rD -> s2
    fused_kernel<<<dim3(SCHF), dim3(512), 0, stream>>>(Wh, Xh, wvz, parts);
    reduce_kernel<<<dim3(B_ * 8), dim3(256), 0, stream>>>(parts, wvz, out, SCHF, 2);

    (void)in_sizes; (void)n_in; (void)out_size; (void)ws_size;
}

// Round 7
// 297.874 us; speedup vs baseline: 4.2305x; 4.2305x over previous
//
#include <hip/hip_runtime.h>

// CapsuleLayer dynamic routing, MI355X (gfx950).
// B=64, I=2048 (input caps), L=16 (in_dim), J=64 (out caps), K=32 (out dim).
// u_hat never materialized. Logits are linear in u_hat (b_r = (sum of prior v).u_hat).
// Pipeline per routing iteration r>0 (R5 skeleton, R7 fixes):
//   zcalc: e[j][i][b] = exp(wv.u_hat) via MFMA (4-deep load pipelining)
//   dsum:  rD[i][b] = 1/sum_j e
//   s:     s partials = sum_i (e*rD)*u_hat -> parts[ch][j][k][b] (COALESCED flush:
//          per acc reg, lanes 0-31 write one full 64B line; R6 showed the old
//          b-major-row scatter cost 11x write amplification)
//   reduce: block=j, lane=b; coalesced parts reads; squash; wv frags update.
// r=0: s0_cast fuses the W fp32->f16 cast (single read of W = HBM floor).
// MFMA 32x32x16 f16: D rows k = (r&3)+8*(r>>2)+4*(lane>>5), cols b = lane&31.

#define B_ 64
#define I_ 2048
#define L_ 16
#define J_ 64
#define K_ 32
#define N_ 2048  // J_*K_

typedef _Float16 half8_t __attribute__((ext_vector_type(8)));
typedef float f32x16 __attribute__((ext_vector_type(16)));
typedef float float4_t __attribute__((ext_vector_type(4)));

__device__ __forceinline__ f32x16 fzero16() {
    f32x16 z;
#pragma unroll
    for (int r = 0; r < 16; ++r) z[r] = 0.f;
    return z;
}

// ---- cast x: [b][i][l] fp32 -> Xh[i][b][l] f16
__global__ __launch_bounds__(256) void cast_x_kernel(const float* __restrict__ X,
                                                     _Float16* __restrict__ Xh) {
    unsigned tid = blockIdx.x * 256u + threadIdx.x;  // (i,b), b fastest
    unsigned b = tid & 63u;
    unsigned i = tid >> 6;
    const float4_t* src = (const float4_t*)(X + (size_t)(b * I_ + i) * L_);
    float4_t f0 = src[0], f1 = src[1], f2 = src[2], f3 = src[3];
    half8_t h0, h1;
#pragma unroll
    for (int e = 0; e < 4; ++e) {
        h0[e] = (_Float16)f0[e];
        h0[4 + e] = (_Float16)f1[e];
        h1[e] = (_Float16)f2[e];
        h1[4 + e] = (_Float16)f3[e];
    }
    _Float16* dst = Xh + (size_t)(i * B_ + b) * L_;
    *(half8_t*)dst = h0;
    *(half8_t*)(dst + 8) = h1;
}

// ---- r0 pass: uniform c (1/64 folded into reduce); fused W fp32 read + f16 cast.
// Grid: SCH*8 blocks x 512 threads; wave owns j = (blk&7)*8 + w, streams i-chunk.
__global__ __launch_bounds__(512) void s0_cast_kernel(const float* __restrict__ Wf,
                                                      _Float16* __restrict__ Wh_out,
                                                      const _Float16* __restrict__ Xh,
                                                      _Float16* __restrict__ parts,
                                                      int SCH, int ICH) {
    const int tid = threadIdx.x;
    const int w = tid >> 6;
    const int l = tid & 63;
    const int h2 = l >> 5;
    const int kb = l & 31;
    const int chunk = blockIdx.x >> 3;
    const int jq = blockIdx.x & 7;
    const int j = jq * 8 + w;

    float s0[16], s1[16];
#pragma unroll
    for (int r = 0; r < 16; ++r) { s0[r] = 0.f; s1[r] = 0.f; }

    const int i0 = chunk * ICH;
    for (int ii = 0; ii < ICH; ++ii) {
        const int i = i0 + ii;
        const _Float16* xb = Xh + (size_t)i * (B_ * L_);
        half8_t xf0 = *(const half8_t*)(xb + kb * L_ + 8 * h2);
        half8_t xf1 = *(const half8_t*)(xb + (32 + kb) * L_ + 8 * h2);
        const float4_t* wsrc =
            (const float4_t*)(Wf + ((size_t)(j * I_ + i) * K_ + kb) * L_ + 8 * h2);
        float4_t a0 = wsrc[0], a1 = wsrc[1];
        half8_t af;
#pragma unroll
        for (int e = 0; e < 4; ++e) {
            af[e] = (_Float16)a0[e];
            af[4 + e] = (_Float16)a1[e];
        }
        *(half8_t*)(Wh_out + ((size_t)(i * J_ + j) * K_ + kb) * L_ + 8 * h2) = af;
        f32x16 acc0 = __builtin_amdgcn_mfma_f32_32x32x16_f16(af, xf0, fzero16(), 0, 0, 0);
        f32x16 acc1 = __builtin_amdgcn_mfma_f32_32x32x16_f16(af, xf1, fzero16(), 0, 0, 0);
#pragma unroll
        for (int r = 0; r < 16; ++r) {
            s0[r] += acc0[r];
            s1[r] += acc1[r];
        }
    }
    // coalesced flush: parts[chunk][j][k][b]; per r, lanes write full 64B lines
#pragma unroll
    for (int r = 0; r < 16; ++r) {
        const int k = (r & 3) + 8 * (r >> 2) + 4 * h2;
        _Float16* p = parts + (((size_t)chunk * J_ + j) * K_ + k) * B_;
        p[kb] = (_Float16)s0[r];
        p[32 + kb] = (_Float16)s1[r];
    }
}

// ---- zcalc: e[j][i][b] = exp(z), z = wv . u_hat. Wave owns j, streams i (4-deep).
// wvz layout: [j][h2][b:64][r:16] f16 where k = (r&3) + 8*(r>>2) + 4*h2.
__global__ __launch_bounds__(512) void zcalc_kernel(const _Float16* __restrict__ Wh,
                                                    const _Float16* __restrict__ Xh,
                                                    const _Float16* __restrict__ wvz,
                                                    _Float16* __restrict__ ebuf,
                                                    int SCH, int ICH) {
    const int tid = threadIdx.x;
    const int w = tid >> 6;
    const int l = tid & 63;
    const int h2 = l >> 5;
    const int kb = l & 31;
    const int chunk = blockIdx.x >> 3;
    const int jq = blockIdx.x & 7;
    const int j = jq * 8 + w;

    const _Float16* wp = wvz + ((size_t)(j * 2 + h2) * B_ + kb) * 16;
    const half8_t wv00 = *(const half8_t*)wp;          // batch kb,    regs 0-7
    const half8_t wv01 = *(const half8_t*)(wp + 8);    // batch kb,    regs 8-15
    const half8_t wv10 = *(const half8_t*)(wp + 512);  // batch kb+32, regs 0-7
    const half8_t wv11 = *(const half8_t*)(wp + 520);

    const int i0 = chunk * ICH;
    for (int ig = 0; ig < ICH; ig += 4) {
        // issue ALL loads for 4 iterations before any consume (MLP)
        half8_t af[4], x0[4], x1[4];
#pragma unroll
        for (int q = 0; q < 4; ++q) {
            const int i = i0 + ig + q;
            const _Float16* xb = Xh + (size_t)i * (B_ * L_);
            x0[q] = *(const half8_t*)(xb + kb * L_ + 8 * h2);
            x1[q] = *(const half8_t*)(xb + (32 + kb) * L_ + 8 * h2);
            af[q] = *(const half8_t*)(Wh + ((size_t)(i * J_ + j) * K_ + kb) * L_ + 8 * h2);
        }
#pragma unroll
        for (int q = 0; q < 4; ++q) {
            const int i = i0 + ig + q;
            f32x16 acc0 = __builtin_amdgcn_mfma_f32_32x32x16_f16(af[q], x0[q], fzero16(), 0, 0, 0);
            f32x16 acc1 = __builtin_amdgcn_mfma_f32_32x32x16_f16(af[q], x1[q], fzero16(), 0, 0, 0);
            // 4 independent partial chains per z (dep depth 4)
            float z0a = 0.f, z0b = 0.f, z0c = 0.f, z0d = 0.f;
            float z1a = 0.f, z1b = 0.f, z1c = 0.f, z1d = 0.f;
#pragma unroll
            for (int r = 0; r < 4; ++r) {
                z0a += acc0[r]      * (float)wv00[r];
                z0b += acc0[r + 4]  * (float)wv00[r + 4];
                z0c += acc0[r + 8]  * (float)wv01[r];
                z0d += acc0[r + 12] * (float)wv01[r + 4];
                z1a += acc1[r]      * (float)wv10[r];
                z1b += acc1[r + 4]  * (float)wv10[r + 4];
                z1c += acc1[r + 8]  * (float)wv11[r];
                z1d += acc1[r + 12] * (float)wv11[r + 4];
            }
            float z0 = (z0a + z0b) + (z0c + z0d);
            float z1 = (z1a + z1b) + (z1c + z1d);
            z0 += __shfl_xor(z0, 32, 64);  // combine disjoint k-halves
            z1 += __shfl_xor(z1, 32, 64);
            const float zf = fminf((l < 32) ? z0 : z1, 11.0f);  // |z|<~6; NaN insurance
            ebuf[((size_t)j * I_ + i) * B_ + l] = (_Float16)__expf(zf);
        }
    }
}

// ---- dsum: rD[i][b] = 1 / sum_j e[j][i][b]. One wave per i, lane = b.
__global__ __launch_bounds__(256) void dsum_kernel(const _Float16* __restrict__ ebuf,
                                                   float* __restrict__ rD) {
    const int w = threadIdx.x >> 6;
    const int l = threadIdx.x & 63;
    const int i = blockIdx.x * 4 + w;
    float p0 = 0.f, p1 = 0.f, p2 = 0.f, p3 = 0.f;
#pragma unroll
    for (int jq = 0; jq < 16; ++jq) {
        p0 += (float)ebuf[((size_t)(jq * 4 + 0) * I_ + i) * B_ + l];
        p1 += (float)ebuf[((size_t)(jq * 4 + 1) * I_ + i) * B_ + l];
        p2 += (float)ebuf[((size_t)(jq * 4 + 2) * I_ + i) * B_ + l];
        p3 += (float)ebuf[((size_t)(jq * 4 + 3) * I_ + i) * B_ + l];
    }
    rD[i * B_ + l] = 1.0f / ((p0 + p1) + (p2 + p3));
}

// ---- S: s partials over an i-chunk, weighted by c = e*rD. 4-deep load pipelining.
__global__ __launch_bounds__(512) void s_kernel(const _Float16* __restrict__ Wh,
                                                const _Float16* __restrict__ Xh,
                                                const _Float16* __restrict__ ebuf,
                                                const float* __restrict__ rD,
                                                _Float16* __restrict__ parts,
                                                int SCH, int ICH) {
    const int tid = threadIdx.x;
    const int w = tid >> 6;
    const int l = tid & 63;
    const int h2 = l >> 5;
    const int kb = l & 31;
    const int chunk = blockIdx.x >> 3;
    const int jq = blockIdx.x & 7;
    const int j = jq * 8 + w;

    float s0[16], s1[16];
#pragma unroll
    for (int r = 0; r < 16; ++r) { s0[r] = 0.f; s1[r] = 0.f; }

    const int i0 = chunk * ICH;
    for (int ig = 0; ig < ICH; ig += 4) {
        half8_t af[4], x0[4], x1[4];
        float e0[4], e1[4], d0[4], d1[4];
#pragma unroll
        for (int q = 0; q < 4; ++q) {
            const int i = i0 + ig + q;
            const _Float16* xb = Xh + (size_t)i * (B_ * L_);
            x0[q] = *(const half8_t*)(xb + kb * L_ + 8 * h2);
            x1[q] = *(const half8_t*)(xb + (32 + kb) * L_ + 8 * h2);
            af[q] = *(const half8_t*)(Wh + ((size_t)(i * J_ + j) * K_ + kb) * L_ + 8 * h2);
            const _Float16* ep = ebuf + ((size_t)j * I_ + i) * B_;
            e0[q] = (float)ep[kb];
            e1[q] = (float)ep[32 + kb];
            d0[q] = rD[i * B_ + kb];
            d1[q] = rD[i * B_ + 32 + kb];
        }
#pragma unroll
        for (int q = 0; q < 4; ++q) {
            f32x16 acc0 = __builtin_amdgcn_mfma_f32_32x32x16_f16(af[q], x0[q], fzero16(), 0, 0, 0);
            f32x16 acc1 = __builtin_amdgcn_mfma_f32_32x32x16_f16(af[q], x1[q], fzero16(), 0, 0, 0);
            const float c0 = e0[q] * d0[q];
            const float c1 = e1[q] * d1[q];
#pragma unroll
            for (int r = 0; r < 16; ++r) {
                s0[r] += c0 * acc0[r];
                s1[r] += c1 * acc1[r];
            }
        }
    }
    // coalesced flush: parts[chunk][j][k][b]
#pragma unroll
    for (int r = 0; r < 16; ++r) {
        const int k = (r & 3) + 8 * (r >> 2) + 4 * h2;
        _Float16* p = parts + (((size_t)chunk * J_ + j) * K_ + k) * B_;
        p[kb] = (_Float16)s0[r];
        p[32 + kb] = (_Float16)s1[r];
    }
}

// ---- reduce: block = j (grid 64), 512 threads: b = t&63, kg = t>>6, k = kg*4+q.
// Coalesced parts reads (lane-consecutive b). Squash over k via tiny LDS.
// STEP0: s *= 1/64, wvz = v. STEP1: wvz += v. STEP2: out = v.
__global__ __launch_bounds__(512) void reduce_kernel(const _Float16* __restrict__ parts,
                                                     _Float16* __restrict__ wvz,
                                                     float* __restrict__ out,
                                                     int SCH, int STEP) {
    __shared__ float ssql[8][64];
    const int j = blockIdx.x;
    const int t = threadIdx.x;
    const int b = t & 63;
    const int kg = t >> 6;  // k = kg*4 + q, q in [0,4)

    float acc[4] = {0.f, 0.f, 0.f, 0.f};
    for (int ch = 0; ch < SCH; ++ch) {
        const _Float16* p = parts + (((size_t)ch * J_ + j) * K_ + kg * 4) * B_ + b;
#pragma unroll
        for (int q = 0; q < 4; ++q) acc[q] += (float)p[(size_t)q * B_];
    }
    if (STEP == 0) {
#pragma unroll
        for (int q = 0; q < 4; ++q) acc[q] *= (1.0f / 64.0f);
    }
    ssql[kg][b] = acc[0] * acc[0] + acc[1] * acc[1] + acc[2] * acc[2] + acc[3] * acc[3];
    __syncthreads();
    float sq = 0.f;
#pragma unroll
    for (int g = 0; g < 8; ++g) sq += ssql[g][b];
    const float scale = sq / (1.0f + sq) / sqrtf(sq + 1e-7f);

    if (STEP == 2) {
#pragma unroll
        for (int q = 0; q < 4; ++q)
            out[(size_t)b * N_ + j * K_ + kg * 4 + q] = acc[q] * scale;
    } else {
        // k = kg*4+q -> h2 = kg&1, r = q + 4*(kg>>1)
        _Float16* wp = wvz + ((size_t)(j * 2 + (kg & 1)) * B_ + b) * 16 + 4 * (kg >> 1);
#pragma unroll
        for (int q = 0; q < 4; ++q) {
            const float prev = (STEP == 0) ? 0.f : (float)wp[q];
            wp[q] = (_Float16)(prev + acc[q] * scale);
        }
    }
}

extern "C" void kernel_launch(void* const* d_in, const int* in_sizes, int n_in,
                              void* d_out, int out_size, void* d_ws, size_t ws_size,
                              hipStream_t stream) {
    const float* X = (const float*)d_in[0];  // [64][2048][16]
    const float* W = (const float*)d_in[1];  // [64][2048][32][16]
    float* out = (float*)d_out;              // [64][64][32]
    char* ws = (char*)d_ws;

    const size_t WH_BYTES = (size_t)I_ * J_ * K_ * L_ * 2;   // 134,217,728
    const size_t XH_BYTES = (size_t)I_ * B_ * L_ * 2;        //   4,194,304
    const size_t WVZ_BYTES = (size_t)J_ * 2 * B_ * 16 * 2;   //     262,144
    const size_t EB_BYTES = (size_t)J_ * I_ * B_ * 2;        //  16,777,216
    const size_t RD_BYTES = (size_t)I_ * B_ * 4;             //     524,288
    const size_t FIX = WH_BYTES + XH_BYTES + WVZ_BYTES + EB_BYTES + RD_BYTES;

    int SCH = 64;  // parts chunks; parts = SCH*N*B f16
    if (ws_size < FIX + (size_t)64 * N_ * B_ * 2) SCH = 32;
    if (ws_size < FIX + (size_t)32 * N_ * B_ * 2) SCH = 16;
    const int ICH = I_ / SCH;

    _Float16* Wh = (_Float16*)ws;
    _Float16* Xh = (_Float16*)(ws + WH_BYTES);
    _Float16* wvz = (_Float16*)(ws + WH_BYTES + XH_BYTES);
    _Float16* ebuf = (_Float16*)(ws + WH_BYTES + XH_BYTES + WVZ_BYTES);
    float* rD = (float*)(ws + WH_BYTES + XH_BYTES + WVZ_BYTES + EB_BYTES);
    _Float16* parts = (_Float16*)(ws + FIX);

    cast_x_kernel<<<dim3((B_ * I_) / 256), dim3(256), 0, stream>>>(X, Xh);

    // r = 0: uniform c; fused fp32 read + cast + s0
    s0_cast_kernel<<<dim3(SCH * 8), dim3(512), 0, stream>>>(W, Wh, Xh, parts, SCH, ICH);
    reduce_kernel<<<dim3(J_), dim3(512), 0, stream>>>(parts, wvz, out, SCH, 0);

    // r = 1: e = exp(v0 . u_hat); rD; s1
    zcalc_kernel<<<dim3(SCH * 8), dim3(512), 0, stream>>>(Wh, Xh, wvz, ebuf, SCH, ICH);
    dsum_kernel<<<dim3(I_ / 4), dim3(256), 0, stream>>>(ebuf, rD);
    s_kernel<<<dim3(SCH * 8), dim3(512), 0, stream>>>(Wh, Xh, ebuf, rD, parts, SCH, ICH);
    reduce_kernel<<<dim3(J_), dim3(512), 0, stream>>>(parts, wvz, out, SCH, 1);

    // r = 2: e = exp((v0+v1) . u_hat); rD; s2
    zcalc_kernel<<<dim3(SCH * 8), dim3(512), 0, stream>>>(Wh, Xh, wvz, ebuf, SCH, ICH);
    dsum_kernel<<<dim3(I_ / 4), dim3(256), 0, stream>>>(ebuf, rD);
    s_kernel<<<dim3(SCH * 8), dim3(512), 0, stream>>>(Wh, Xh, ebuf, rD, parts, SCH, ICH);
    reduce_kernel<<<dim3(J_), dim3(512), 0, stream>>>(parts, wvz, out, SCH, 2);

    (void)in_sizes; (void)n_in; (void)out_size;
}